// Round 2
// baseline (205.773 us; speedup 1.0000x reference)
//
#include <hip/hip_runtime.h>
#include <hip/hip_fp16.h>

#define G 128

typedef _Float16 h2_t __attribute__((ext_vector_type(2)));

union U16 { uint4 u; h2_t h2[4]; };
union HV  { uint4 u; h2_t h2[4]; };
union PK2 { uint2 u; h2_t h[2]; };

__device__ __forceinline__ float dot2f(h2_t a, h2_t b, float c) {
#if __has_builtin(__builtin_amdgcn_fdot2)
    return __builtin_amdgcn_fdot2(a, b, c, false);
#else
    return c + (float)a.x * (float)b.x + (float)a.y * (float)b.y;
#endif
}

__device__ __forceinline__ float dot4(float4 a, float4 b) {
    return a.x * b.x + a.y * b.y + a.z * b.z + a.w * b.w;
}

// ---------------------------------------------------------------------------
// Kernel A: fused conv1 (3x3x3, 1->16, SAME) + relu + m0-mask + 2x2x2 maxpool.
// Round-2 changes vs round-1 (which was ~34us, ~2.4x over its 14us BW floor):
//  * REGISTER-STAGED loads: all 10 16B global loads (5 occ int4 + 5 x float4)
//    issued back-to-back into reg arrays BEFORE any LDS write -> 10 in flight
//    per thread vs ~2 (the old load->convert->ds_write interleave serialized
//    on vmcnt). This was the latency bottleneck: VALU+LDS arithmetic accounts
//    for <3us of the 34.
//  * Compaction phase DELETED: the active list + per-cell m1 byte mask are
//    built in the staging write loop from the occ bits already in registers
//    (removes smB 4.3KB, 8 ballots + 8 LDS byte reads/thread, one barrier
//    phase). LDS 33.4 -> 30.2 KB => 5 blocks/CU.
//  * Weights converted per-block into LDS (drops k_prep dispatch + gap);
//    inner-loop weight reads are uniform-address LDS broadcasts (no conflict).
// Phases: zero/weights | sync | stage+list | sync | compute+atomicMax | sync
// | epilogue. atomicMax on int-bits of relu'd f32 is valid (relu>=0 =>
// float bits monotonic); fp16->f32->fp16 roundtrip is lossless.
// ---------------------------------------------------------------------------
__global__ __launch_bounds__(256, 4)
void k_conv1_pool(const float* __restrict__ x, const int* __restrict__ occ,
                  const float* __restrict__ W1,
                  __half* __restrict__ h1p, float* __restrict__ m1)
{
    // sx: (lz,ly,lx) at (lz*18+ly)*24 + lx, lx in [0,24); gx = bx*16 - 4 + lx
    __shared__ __align__(16) _Float16      sx[10 * 18 * 24];   // 8640 B
    __shared__ __align__(16) int           pacc[16 * 256];     // 16 KB [ch][cell]
    __shared__ __align__(4)  unsigned short slist[2048];       // 4 KB
    __shared__ __align__(16) h2_t          w1L[216];           // 864 B
    __shared__ __align__(4)  unsigned char sm1[256];
    __shared__ int                         scnt;

    const int bx = blockIdx.x, by = blockIdx.y;
    const int b  = blockIdx.z >> 4, zt = blockIdx.z & 15;
    const int tid = threadIdx.x;

    const int z0 = zt * 8 - 1, y0 = by * 16 - 1;
    const int base_b = b * G * G * G;

    // ---- issue ALL staging loads first (nothing dependent between them) ----
    int4   ro[5];
    float4 rx[5];
    #pragma unroll
    for (int it = 0; it < 5; ++it) {
        int c = it * 256 + tid;
        int cc = c < 1080 ? c : 1079;          // clamp: harmless duplicate load
        int row = cc / 6, seg = cc - row * 6;  // row in [0,180)
        int lz  = row / 18, ly = row - lz * 18;
        int gz = z0 + lz, gy = y0 + ly;
        int gxc = (bx << 4) - 4 + (seg << 2);
        bool inb = (unsigned)gz < 128u && (unsigned)gy < 128u && (unsigned)gxc < 128u;
        int gi = inb ? base_b + (gz * G + gy) * G + gxc : base_b;  // safe addr
        ro[it] = *(const int4*)(occ + gi);
        rx[it] = *(const float4*)(x + gi);
    }

    // ---- phase 0 LDS init (independent of the loads above) ----
    if (tid == 0) scnt = 0;
    {
        uint4 z4 = make_uint4(0u, 0u, 0u, 0u);
        uint4* p4 = (uint4*)pacc;
        p4[tid] = z4; p4[tid + 256] = z4; p4[tid + 512] = z4; p4[tid + 768] = z4;
    }
    if (tid < 64) ((unsigned*)sm1)[tid] = 0u;
    if (tid < 216) {
        float2 f = ((const float2*)W1)[tid];   // w1L[i] = (W1[2i], W1[2i+1])
        h2_t w; w.x = (_Float16)f.x; w.y = (_Float16)f.y;
        w1L[tid] = w;
    }
    __syncthreads();   // zero/init visible before list atomics & sm1 writes

    // ---- write loop: convert + LDS store + build active list in one pass ----
    #pragma unroll
    for (int it = 0; it < 5; ++it) {
        int c = it * 256 + tid;
        if (c < 1080) {
            int row = c / 6, seg = c - row * 6;
            int lz  = row / 18, ly = row - lz * 18;
            int gz = z0 + lz, gy = y0 + ly;
            int gxc = (bx << 4) - 4 + (seg << 2);
            bool inb = (unsigned)gz < 128u && (unsigned)gy < 128u && (unsigned)gxc < 128u;
            int4   o4 = ro[it];
            float4 x4 = rx[it];
            if (!inb) o4 = make_int4(1, 1, 1, 1);
            h2_t p01, p23;
            p01.x = (o4.x == 0) ? (_Float16)x4.x : (_Float16)0.f;
            p01.y = (o4.y == 0) ? (_Float16)x4.y : (_Float16)0.f;
            p23.x = (o4.z == 0) ? (_Float16)x4.z : (_Float16)0.f;
            p23.y = (o4.w == 0) ? (_Float16)x4.w : (_Float16)0.f;
            PK2 pk; pk.h[0] = p01; pk.h[1] = p23;
            *(uint2*)&sx[row * 24 + (seg << 2)] = pk.u;

            // interior chunks (lz 1..8, ly 1..16, seg 1..4) feed the list;
            // they are always fully in-bounds so o4 is real data.
            if ((unsigned)(lz - 1) < 8u && (unsigned)(ly - 1) < 16u &&
                (unsigned)(seg - 1) < 4u) {
                int mb = (o4.x == 0 ? 1 : 0) | (o4.y == 0 ? 2 : 0) |
                         (o4.z == 0 ? 4 : 0) | (o4.w == 0 ? 8 : 0);
                if (mb) {
                    int cnt  = __popc(mb);
                    int base = atomicAdd(&scnt, cnt);
                    int cz = lz - 1, cy = ly - 1, cx0v = (seg << 2) - 4;
                    int cellb = (cz >> 1) * 64 + (cy >> 1) * 8;
                    #pragma unroll
                    for (int j = 0; j < 4; ++j) {
                        if (mb & (1 << j)) {
                            slist[base++] = (unsigned short)((cz << 8) | (cy << 4) | (cx0v + j));
                            sm1[cellb + ((cx0v + j) >> 1)] = (unsigned char)1;  // benign race: all write 1
                        }
                    }
                }
            }
        }
    }
    __syncthreads();

    const int n = scnt;   // ~205 of 2048 at 10% density

    // ---- compute: one ACTIVE center per thread ----
    const h2_t zero = (h2_t)(_Float16)0.f;
    for (int kb = 0; kb < n; kb += 256) {
        const int idx = kb + tid;
        if (idx < n) {
            const int code = slist[idx];
            const int cz = code >> 8, cy = (code >> 4) & 15, cx = code & 15;
            const int sb = ((cz + 1) * 18 + (cy + 1)) * 24 + cx + 4;
            h2_t acc[8];
            #pragma unroll
            for (int c = 0; c < 8; ++c) acc[c] = zero;
            #pragma unroll
            for (int kz = 0; kz < 3; ++kz)
            #pragma unroll
            for (int ky = 0; ky < 3; ++ky)
            #pragma unroll
            for (int kx = 0; kx < 3; ++kx) {
                _Float16 v = sx[sb + (kz - 1) * 432 + (ky - 1) * 24 + (kx - 1)];
                h2_t v2 = {v, v};
                const h2_t* w = &w1L[((kz * 3 + ky) * 3 + kx) * 8];  // uniform -> broadcast
                #pragma unroll
                for (int c = 0; c < 8; ++c) acc[c] = v2 * w[c] + acc[c];
            }
            const int cell = (cz >> 1) * 64 + (cy >> 1) * 8 + (cx >> 1);
            #pragma unroll
            for (int c = 0; c < 8; ++c) {
                atomicMax(&pacc[(2 * c) * 256 + cell],
                          __float_as_int(fmaxf((float)acc[c].x, 0.f)));
                atomicMax(&pacc[(2 * c + 1) * 256 + cell],
                          __float_as_int(fmaxf((float)acc[c].y, 0.f)));
            }
        }
    }
    __syncthreads();

    // ---- epilogue: pooled cell tid -> h1p (fp16 x16) + m1 ----
    const int tx = tid & 7, ty = (tid >> 3) & 7, tz = tid >> 6;
    const int pz = zt * 4 + tz, py = by * 8 + ty, px = bx * 8 + tx;
    const int vidx = ((b * 64 + pz) * 64 + py) * 64 + px;
    HV p0, p1;
    #pragma unroll
    for (int c = 0; c < 4; ++c) {
        h2_t a, bq;
        a.x  = (_Float16)__int_as_float(pacc[(2 * c) * 256 + tid]);
        a.y  = (_Float16)__int_as_float(pacc[(2 * c + 1) * 256 + tid]);
        bq.x = (_Float16)__int_as_float(pacc[(8 + 2 * c) * 256 + tid]);
        bq.y = (_Float16)__int_as_float(pacc[(9 + 2 * c) * 256 + tid]);
        p0.h2[c] = a; p1.h2[c] = bq;
    }
    uint4* o = (uint4*)&h1p[(size_t)vidx * 16];
    o[0] = p0.u;
    o[1] = p1.u;
    m1[vidx] = sm1[tid] ? 1.f : 0.f;
}

// ---------------------------------------------------------------------------
// Kernel B: fused conv2 (3x3x3, 16->4) + relu + m1-mask + pool + FULL DECODER.
// Round-2 changes:
//  * Single-pass staging of BOTH channel halves (tile[half][voxel], 35.2 KB)
//    -> barriers per block 4 -> 2; compute loop consumes all 16 channels per
//    tap. [half][voxel] layout keeps the uniform 8-column bank distribution.
//  * REGISTER-STAGED tile loads (10 x 16B in flight before any ds_write).
//  * W2 converted per-block into LDS (k_prep dropped); weight reads in the
//    inner loop are uniform-address LDS broadcasts.
// LDS ~42.5 KB -> 3 blocks/CU (12 waves); in-flight bytes/CU unchanged vs the
// old 6-block 2-pass layout, with half the barrier count.
// ---------------------------------------------------------------------------
__global__ __launch_bounds__(256)
void k_conv2_dec(const __half* __restrict__ h1p, const float* __restrict__ m1,
                 const float* __restrict__ W2,
                 const float* __restrict__ Wt1, const float* __restrict__ Wt2,
                 float* __restrict__ out)
{
    __shared__ uint4  tile[2200];   // [half][10*10*11], 35.2 KB
    __shared__ float4 wt1[128];     // Wt1: 512 floats
    __shared__ float4 wt2[32];      // Wt2: 128 floats
    __shared__ __align__(16) h2_t w2L[864];  // 3456 B
    __shared__ float4 sh_h[64];
    __shared__ float  sh_m[64];

    const int bx = blockIdx.x, by = blockIdx.y;
    const int b  = blockIdx.z >> 3, bz = blockIdx.z & 7;
    const int tid = threadIdx.x;

    const int z0 = bz * 8 - 1, y0 = by * 8 - 1, x0 = bx * 8 - 1;

    // ---- issue all tile loads first (reg-staged, max MLP) ----
    uint4 ra[5], rb4[5];
    #pragma unroll
    for (int it = 0; it < 5; ++it) {
        int g = it * 256 + tid;
        int gg = g < 1100 ? g : 1099;
        int z = gg / 110, r = gg - z * 110, y = r / 11, xx = r - y * 11;
        int gz = z0 + z, gy = y0 + y, gx = x0 + xx;
        bool inb = (unsigned)gz < 64u && (unsigned)gy < 64u && (unsigned)gx < 64u;
        size_t vi = inb ? (size_t)(((b * 64 + gz) * 64 + gy) * 64 + gx) : 0;
        const uint4* src = (const uint4*)&h1p[vi * 16];
        ra[it]  = src[0];
        rb4[it] = src[1];
    }

    // ---- weights to LDS (their latency hides under tile loads in flight) ----
    if (tid < 128) wt1[tid] = ((const float4*)Wt1)[tid];
    if (tid < 32)  wt2[tid] = ((const float4*)Wt2)[tid];
    #pragma unroll
    for (int it = 0; it < 4; ++it) {
        int i = it * 256 + tid;
        if (i < 864) {
            int t = i >> 5, rr = i & 31, co = rr >> 3, p = rr & 7;
            h2_t w;
            w.x = (_Float16)W2[t * 64 + (2 * p) * 4 + co];
            w.y = (_Float16)W2[t * 64 + (2 * p + 1) * 4 + co];
            w2L[i] = w;
        }
    }

    // ---- tile write loop ----
    #pragma unroll
    for (int it = 0; it < 5; ++it) {
        int g = it * 256 + tid;
        if (g < 1100) {
            int z = g / 110, r = g - z * 110, y = r / 11, xx = r - y * 11;
            int gz = z0 + z, gy = y0 + y, gx = x0 + xx;
            bool inb = (unsigned)gz < 64u && (unsigned)gy < 64u && (unsigned)gx < 64u;
            uint4 a0 = ra[it], a1 = rb4[it];
            if (!inb) { a0 = make_uint4(0u, 0u, 0u, 0u); a1 = a0; }
            tile[g]        = a0;
            tile[1100 + g] = a1;
        }
    }
    __syncthreads();

    const int dy = tid & 1, dz = (tid >> 1) & 1;
    const int qx = (tid >> 2) & 3, Y = (tid >> 4) & 3, Z = (tid >> 6) & 3;
    const int cx0 = 2 * qx, cy = 2 * Y + dy, cz = 2 * Z + dz;

    float acc[2][4] = {{0.f, 0.f, 0.f, 0.f}, {0.f, 0.f, 0.f, 0.f}};

    #pragma unroll
    for (int kz = 0; kz < 3; ++kz)
    #pragma unroll
    for (int ky = 0; ky < 3; ++ky) {
        const int rb = (cz + kz) * 110 + (cy + ky) * 11 + cx0;
        h2_t hp[2][4][4];
        #pragma unroll
        for (int hh = 0; hh < 2; ++hh)
        #pragma unroll
        for (int xi = 0; xi < 4; ++xi) {
            U16 a; a.u = tile[hh * 1100 + rb + xi];
            #pragma unroll
            for (int p = 0; p < 4; ++p) hp[hh][xi][p] = a.h2[p];
        }
        const int t3 = (kz * 3 + ky) * 3;
        #pragma unroll
        for (int kx = 0; kx < 3; ++kx) {
            const h2_t* w = &w2L[(t3 + kx) * 32];   // uniform -> LDS broadcast
            #pragma unroll
            for (int j = 0; j < 2; ++j) {
                #pragma unroll
                for (int co = 0; co < 4; ++co) {
                    float a = acc[j][co];
                    #pragma unroll
                    for (int hh = 0; hh < 2; ++hh)
                    #pragma unroll
                    for (int p = 0; p < 4; ++p)
                        a = dot2f(hp[hh][kx + j][p], w[co * 8 + 4 * hh + p], a);
                    acc[j][co] = a;
                }
            }
        }
    }

    // ---- mask + relu + pool ----
    const int gcz = bz * 8 + cz, gcy = by * 8 + cy, gcx = bx * 8 + cx0;
    const float mv0 = m1[((b * 64 + gcz) * 64 + gcy) * 64 + gcx];
    const float mv1 = m1[((b * 64 + gcz) * 64 + gcy) * 64 + gcx + 1];
    float m = fmaxf(mv0, mv1);
    float r0 = fmaxf(fmaxf(acc[0][0], 0.f) * mv0, fmaxf(acc[1][0], 0.f) * mv1);
    float r1 = fmaxf(fmaxf(acc[0][1], 0.f) * mv0, fmaxf(acc[1][1], 0.f) * mv1);
    float r2 = fmaxf(fmaxf(acc[0][2], 0.f) * mv0, fmaxf(acc[1][2], 0.f) * mv1);
    float r3 = fmaxf(fmaxf(acc[0][3], 0.f) * mv0, fmaxf(acc[1][3], 0.f) * mv1);

    #pragma unroll
    for (int mask = 1; mask <= 2; mask <<= 1) {
        r0 = fmaxf(r0, __shfl_xor(r0, mask));
        r1 = fmaxf(r1, __shfl_xor(r1, mask));
        r2 = fmaxf(r2, __shfl_xor(r2, mask));
        r3 = fmaxf(r3, __shfl_xor(r3, mask));
        m  = fmaxf(m,  __shfl_xor(m,  mask));
    }
    if ((tid & 3) == 0) {
        int p = Z * 16 + Y * 4 + qx;
        sh_h[p] = make_float4(r0, r1, r2, r3);
        sh_m[p] = m;
    }
    __syncthreads();

    // ---- decoder phase: thread = (parent p, a, bb) ----
    {
        const int p  = tid >> 2;
        const int a  = (tid >> 1) & 1;
        const int bb = tid & 1;
        const int pZ = p >> 4, pY = (p >> 2) & 3, pq = p & 3;
        const int pz = bz * 4 + pZ, py = by * 4 + pY, pxq = bx * 4 + pq;

        const float mm = sh_m[p];
        const float4 hv = sh_h[p];

        const int b0q = ((((1 - a) * 2 + (1 - bb)) * 2) + 1) * 16;  // c=0 -> kc=1
        const int b1q = ((((1 - a) * 2 + (1 - bb)) * 2) + 0) * 16;  // c=1 -> kc=0
        float4 t0q[4], t1q[4];
        #pragma unroll
        for (int q = 0; q < 4; ++q) {
            float4 a0 = wt1[b0q + q],      a1 = wt1[b0q + 4 + q];
            float4 a2 = wt1[b0q + 8 + q],  a3 = wt1[b0q + 12 + q];
            float4 c0 = wt1[b1q + q],      c1 = wt1[b1q + 4 + q];
            float4 c2 = wt1[b1q + 8 + q],  c3 = wt1[b1q + 12 + q];
            float4 s0, s1;
            s0.x = hv.x * a0.x + hv.y * a1.x + hv.z * a2.x + hv.w * a3.x;
            s0.y = hv.x * a0.y + hv.y * a1.y + hv.z * a2.y + hv.w * a3.y;
            s0.z = hv.x * a0.z + hv.y * a1.z + hv.z * a2.z + hv.w * a3.z;
            s0.w = hv.x * a0.w + hv.y * a1.w + hv.z * a2.w + hv.w * a3.w;
            s1.x = hv.x * c0.x + hv.y * c1.x + hv.z * c2.x + hv.w * c3.x;
            s1.y = hv.x * c0.y + hv.y * c1.y + hv.z * c2.y + hv.w * c3.y;
            s1.z = hv.x * c0.z + hv.y * c1.z + hv.z * c2.z + hv.w * c3.z;
            s1.w = hv.x * c0.w + hv.y * c1.w + hv.z * c2.w + hv.w * c3.w;
            t0q[q] = make_float4(fmaxf(s0.x, 0.f), fmaxf(s0.y, 0.f),
                                 fmaxf(s0.z, 0.f), fmaxf(s0.w, 0.f));
            t1q[q] = make_float4(fmaxf(s1.x, 0.f), fmaxf(s1.y, 0.f),
                                 fmaxf(s1.z, 0.f), fmaxf(s1.w, 0.f));
        }

        #pragma unroll
        for (int e = 0; e < 2; ++e) {
            #pragma unroll
            for (int f = 0; f < 2; ++f) {
                const int d  = 4 * pz + 2 * a + e;
                const int hh = 4 * py + 2 * bb + f;
                const int be = ((1 - e) * 2 + (1 - f)) * 2;
                const float4* wg0 = &wt2[(be + 1) * 4];   // g=0 -> kg=1
                const float4* wg1 = &wt2[(be + 0) * 4];   // g=1 -> kg=0
                float s00 = dot4(t0q[0], wg0[0]) + dot4(t0q[1], wg0[1])
                          + dot4(t0q[2], wg0[2]) + dot4(t0q[3], wg0[3]);
                float s01 = dot4(t0q[0], wg1[0]) + dot4(t0q[1], wg1[1])
                          + dot4(t0q[2], wg1[2]) + dot4(t0q[3], wg1[3]);
                float s10 = dot4(t1q[0], wg0[0]) + dot4(t1q[1], wg0[1])
                          + dot4(t1q[2], wg0[2]) + dot4(t1q[3], wg0[3]);
                float s11 = dot4(t1q[0], wg1[0]) + dot4(t1q[1], wg1[1])
                          + dot4(t1q[2], wg1[2]) + dot4(t1q[3], wg1[3]);
                float4 o;
                o.x = mm / (1.f + __expf(-s00));
                o.y = mm / (1.f + __expf(-s01));
                o.z = mm / (1.f + __expf(-s10));
                o.w = mm / (1.f + __expf(-s11));
                *(float4*)&out[((b * G + d) * G + hh) * G + 4 * pxq] = o;
            }
        }
    }
}

extern "C" void kernel_launch(void* const* d_in, const int* in_sizes, int n_in,
                              void* d_out, int out_size, void* d_ws, size_t ws_size,
                              hipStream_t stream) {
    (void)in_sizes; (void)n_in; (void)out_size; (void)ws_size;
    const float* x   = (const float*)d_in[0];
    const float* W1  = (const float*)d_in[1];
    const float* W2  = (const float*)d_in[2];
    const float* Wt1 = (const float*)d_in[3];
    const float* Wt2 = (const float*)d_in[4];
    const int*   occ = (const int*)d_in[5];
    float* out = (float*)d_out;

    char* ws = (char*)d_ws;
    __half* h1p = (__half*)ws;                                  // 16 MB
    float*  m1  = (float*)(ws + 8388608ull * sizeof(__half));   // 2 MB

    k_conv1_pool<<<dim3(8, 8, 32), dim3(256), 0, stream>>>(x, occ, W1, h1p, m1);
    k_conv2_dec<<<dim3(8, 8, 16), dim3(256), 0, stream>>>(h1p, m1, W2, Wt1, Wt2, out);
}

// Round 3
// 146.297 us; speedup vs baseline: 1.4065x; 1.4065x over previous
//
#include <hip/hip_runtime.h>
#include <hip/hip_fp16.h>

#define G 128

typedef _Float16 h2_t __attribute__((ext_vector_type(2)));

union U16 { uint4 u; h2_t h2[4]; };
union HV  { uint4 u; h2_t h2[4]; };
union PK2 { uint2 u; h2_t h[2]; };

__device__ __forceinline__ float dot2f(h2_t a, h2_t b, float c) {
#if __has_builtin(__builtin_amdgcn_fdot2)
    return __builtin_amdgcn_fdot2(a, b, c, false);
#else
    return c + (float)a.x * (float)b.x + (float)a.y * (float)b.y;
#endif
}

__device__ __forceinline__ float dot4(float4 a, float4 b) {
    return a.x * b.x + a.y * b.y + a.z * b.z + a.w * b.w;
}

// ---------------------------------------------------------------------------
// Kernel A: fused conv1 (3x3x3, 1->16, SAME) + relu + m0-mask + 2x2x2 maxpool.
//
// ROUND-3 FIX: __launch_bounds__(256,4) -> (256,1). Round-2 counters showed
// VGPR_Count=64 + WRITE_SIZE=247MB (vs 18.4MB real output): the (256,4)
// occupancy demand capped VGPRs at 64, and the 40-reg staging arrays
// (ro[5]+rx[5]) SPILLED TO SCRATCH -> ~230MB of HBM round-trip = the whole
// 102us. Register staging and tight launch-bounds are mutually exclusive.
// With (256,1) the allocator can use ~100-160 VGPR (no spill); occupancy is
// then governed by LDS 30.2KB (<=5 blk/CU) / VGPR (3-4 blk/CU at 128-160),
// which rounds 0-1 showed is enough latency hiding for this kernel.
//
// Structure (unchanged from round 2):
//  * reg-staged loads: all 10 16B loads (5 occ int4 + 5 x float4) in flight
//    before any LDS write.
//  * active-center list + per-cell m1 mask built during the staging write
//    loop from occ bits already in registers (no separate compaction pass).
//  * weights converted per-block into LDS; inner-loop weight reads are
//    uniform-address LDS broadcasts (conflict-free).
//  * pool via LDS atomicMax on int-bits of relu'd f32 (relu>=0 => monotonic),
//    channel-major pacc[ch][cell]; fp16->f32->fp16 is lossless.
// ---------------------------------------------------------------------------
__global__ __launch_bounds__(256, 1)
void k_conv1_pool(const float* __restrict__ x, const int* __restrict__ occ,
                  const float* __restrict__ W1,
                  __half* __restrict__ h1p, float* __restrict__ m1)
{
    // sx: (lz,ly,lx) at (lz*18+ly)*24 + lx, lx in [0,24); gx = bx*16 - 4 + lx
    __shared__ __align__(16) _Float16      sx[10 * 18 * 24];   // 8640 B
    __shared__ __align__(16) int           pacc[16 * 256];     // 16 KB [ch][cell]
    __shared__ __align__(4)  unsigned short slist[2048];       // 4 KB
    __shared__ __align__(16) h2_t          w1L[216];           // 864 B
    __shared__ __align__(4)  unsigned char sm1[256];
    __shared__ int                         scnt;

    const int bx = blockIdx.x, by = blockIdx.y;
    const int b  = blockIdx.z >> 4, zt = blockIdx.z & 15;
    const int tid = threadIdx.x;

    const int z0 = zt * 8 - 1, y0 = by * 16 - 1;
    const int base_b = b * G * G * G;

    // ---- issue ALL staging loads first (nothing dependent between them) ----
    int4   ro[5];
    float4 rx[5];
    #pragma unroll
    for (int it = 0; it < 5; ++it) {
        int c = it * 256 + tid;
        int cc = c < 1080 ? c : 1079;          // clamp: harmless duplicate load
        int row = cc / 6, seg = cc - row * 6;  // row in [0,180)
        int lz  = row / 18, ly = row - lz * 18;
        int gz = z0 + lz, gy = y0 + ly;
        int gxc = (bx << 4) - 4 + (seg << 2);
        bool inb = (unsigned)gz < 128u && (unsigned)gy < 128u && (unsigned)gxc < 128u;
        int gi = inb ? base_b + (gz * G + gy) * G + gxc : base_b;  // safe addr
        ro[it] = *(const int4*)(occ + gi);
        rx[it] = *(const float4*)(x + gi);
    }

    // ---- phase 0 LDS init (independent of the loads above) ----
    if (tid == 0) scnt = 0;
    {
        uint4 z4 = make_uint4(0u, 0u, 0u, 0u);
        uint4* p4 = (uint4*)pacc;
        p4[tid] = z4; p4[tid + 256] = z4; p4[tid + 512] = z4; p4[tid + 768] = z4;
    }
    if (tid < 64) ((unsigned*)sm1)[tid] = 0u;
    if (tid < 216) {
        float2 f = ((const float2*)W1)[tid];   // w1L[i] = (W1[2i], W1[2i+1])
        h2_t w; w.x = (_Float16)f.x; w.y = (_Float16)f.y;
        w1L[tid] = w;
    }
    __syncthreads();   // zero/init visible before list atomics & sm1 writes

    // ---- write loop: convert + LDS store + build active list in one pass ----
    #pragma unroll
    for (int it = 0; it < 5; ++it) {
        int c = it * 256 + tid;
        if (c < 1080) {
            int row = c / 6, seg = c - row * 6;
            int lz  = row / 18, ly = row - lz * 18;
            int gz = z0 + lz, gy = y0 + ly;
            int gxc = (bx << 4) - 4 + (seg << 2);
            bool inb = (unsigned)gz < 128u && (unsigned)gy < 128u && (unsigned)gxc < 128u;
            int4   o4 = ro[it];
            float4 x4 = rx[it];
            if (!inb) o4 = make_int4(1, 1, 1, 1);
            h2_t p01, p23;
            p01.x = (o4.x == 0) ? (_Float16)x4.x : (_Float16)0.f;
            p01.y = (o4.y == 0) ? (_Float16)x4.y : (_Float16)0.f;
            p23.x = (o4.z == 0) ? (_Float16)x4.z : (_Float16)0.f;
            p23.y = (o4.w == 0) ? (_Float16)x4.w : (_Float16)0.f;
            PK2 pk; pk.h[0] = p01; pk.h[1] = p23;
            *(uint2*)&sx[row * 24 + (seg << 2)] = pk.u;

            // interior chunks (lz 1..8, ly 1..16, seg 1..4) feed the list;
            // they are always fully in-bounds so o4 is real data.
            if ((unsigned)(lz - 1) < 8u && (unsigned)(ly - 1) < 16u &&
                (unsigned)(seg - 1) < 4u) {
                int mb = (o4.x == 0 ? 1 : 0) | (o4.y == 0 ? 2 : 0) |
                         (o4.z == 0 ? 4 : 0) | (o4.w == 0 ? 8 : 0);
                if (mb) {
                    int cnt  = __popc(mb);
                    int base = atomicAdd(&scnt, cnt);
                    int cz = lz - 1, cy = ly - 1, cx0v = (seg << 2) - 4;
                    int cellb = (cz >> 1) * 64 + (cy >> 1) * 8;
                    #pragma unroll
                    for (int j = 0; j < 4; ++j) {
                        if (mb & (1 << j)) {
                            slist[base++] = (unsigned short)((cz << 8) | (cy << 4) | (cx0v + j));
                            sm1[cellb + ((cx0v + j) >> 1)] = (unsigned char)1;  // benign race: all write 1
                        }
                    }
                }
            }
        }
    }
    __syncthreads();

    const int n = scnt;   // ~205 of 2048 at 10% density

    // ---- compute: one ACTIVE center per thread ----
    const h2_t zero = (h2_t)(_Float16)0.f;
    for (int kb = 0; kb < n; kb += 256) {
        const int idx = kb + tid;
        if (idx < n) {
            const int code = slist[idx];
            const int cz = code >> 8, cy = (code >> 4) & 15, cx = code & 15;
            const int sb = ((cz + 1) * 18 + (cy + 1)) * 24 + cx + 4;
            h2_t acc[8];
            #pragma unroll
            for (int c = 0; c < 8; ++c) acc[c] = zero;
            #pragma unroll
            for (int kz = 0; kz < 3; ++kz)
            #pragma unroll
            for (int ky = 0; ky < 3; ++ky)
            #pragma unroll
            for (int kx = 0; kx < 3; ++kx) {
                _Float16 v = sx[sb + (kz - 1) * 432 + (ky - 1) * 24 + (kx - 1)];
                h2_t v2 = {v, v};
                const h2_t* w = &w1L[((kz * 3 + ky) * 3 + kx) * 8];  // uniform -> broadcast
                #pragma unroll
                for (int c = 0; c < 8; ++c) acc[c] = v2 * w[c] + acc[c];
            }
            const int cell = (cz >> 1) * 64 + (cy >> 1) * 8 + (cx >> 1);
            #pragma unroll
            for (int c = 0; c < 8; ++c) {
                atomicMax(&pacc[(2 * c) * 256 + cell],
                          __float_as_int(fmaxf((float)acc[c].x, 0.f)));
                atomicMax(&pacc[(2 * c + 1) * 256 + cell],
                          __float_as_int(fmaxf((float)acc[c].y, 0.f)));
            }
        }
    }
    __syncthreads();

    // ---- epilogue: pooled cell tid -> h1p (fp16 x16) + m1 ----
    const int tx = tid & 7, ty = (tid >> 3) & 7, tz = tid >> 6;
    const int pz = zt * 4 + tz, py = by * 8 + ty, px = bx * 8 + tx;
    const int vidx = ((b * 64 + pz) * 64 + py) * 64 + px;
    HV p0, p1;
    #pragma unroll
    for (int c = 0; c < 4; ++c) {
        h2_t a, bq;
        a.x  = (_Float16)__int_as_float(pacc[(2 * c) * 256 + tid]);
        a.y  = (_Float16)__int_as_float(pacc[(2 * c + 1) * 256 + tid]);
        bq.x = (_Float16)__int_as_float(pacc[(8 + 2 * c) * 256 + tid]);
        bq.y = (_Float16)__int_as_float(pacc[(9 + 2 * c) * 256 + tid]);
        p0.h2[c] = a; p1.h2[c] = bq;
    }
    uint4* o = (uint4*)&h1p[(size_t)vidx * 16];
    o[0] = p0.u;
    o[1] = p1.u;
    m1[vidx] = sm1[tid] ? 1.f : 0.f;
}

// ---------------------------------------------------------------------------
// Kernel B: fused conv2 (3x3x3, 16->4) + relu + m1-mask + pool + FULL DECODER.
// UNCHANGED this round (byte-identical to round 2) so next round's counters
// give clean attribution: it should now be the top non-fill dispatch with
// full PMC (dur, VALUBusy, LDS conflicts, VGPR) visible.
// ---------------------------------------------------------------------------
__global__ __launch_bounds__(256)
void k_conv2_dec(const __half* __restrict__ h1p, const float* __restrict__ m1,
                 const float* __restrict__ W2,
                 const float* __restrict__ Wt1, const float* __restrict__ Wt2,
                 float* __restrict__ out)
{
    __shared__ uint4  tile[2200];   // [half][10*10*11], 35.2 KB
    __shared__ float4 wt1[128];     // Wt1: 512 floats
    __shared__ float4 wt2[32];      // Wt2: 128 floats
    __shared__ __align__(16) h2_t w2L[864];  // 3456 B
    __shared__ float4 sh_h[64];
    __shared__ float  sh_m[64];

    const int bx = blockIdx.x, by = blockIdx.y;
    const int b  = blockIdx.z >> 3, bz = blockIdx.z & 7;
    const int tid = threadIdx.x;

    const int z0 = bz * 8 - 1, y0 = by * 8 - 1, x0 = bx * 8 - 1;

    // ---- issue all tile loads first (reg-staged, max MLP) ----
    uint4 ra[5], rb4[5];
    #pragma unroll
    for (int it = 0; it < 5; ++it) {
        int g = it * 256 + tid;
        int gg = g < 1100 ? g : 1099;
        int z = gg / 110, r = gg - z * 110, y = r / 11, xx = r - y * 11;
        int gz = z0 + z, gy = y0 + y, gx = x0 + xx;
        bool inb = (unsigned)gz < 64u && (unsigned)gy < 64u && (unsigned)gx < 64u;
        size_t vi = inb ? (size_t)(((b * 64 + gz) * 64 + gy) * 64 + gx) : 0;
        const uint4* src = (const uint4*)&h1p[vi * 16];
        ra[it]  = src[0];
        rb4[it] = src[1];
    }

    // ---- weights to LDS (their latency hides under tile loads in flight) ----
    if (tid < 128) wt1[tid] = ((const float4*)Wt1)[tid];
    if (tid < 32)  wt2[tid] = ((const float4*)Wt2)[tid];
    #pragma unroll
    for (int it = 0; it < 4; ++it) {
        int i = it * 256 + tid;
        if (i < 864) {
            int t = i >> 5, rr = i & 31, co = rr >> 3, p = rr & 7;
            h2_t w;
            w.x = (_Float16)W2[t * 64 + (2 * p) * 4 + co];
            w.y = (_Float16)W2[t * 64 + (2 * p + 1) * 4 + co];
            w2L[i] = w;
        }
    }

    // ---- tile write loop ----
    #pragma unroll
    for (int it = 0; it < 5; ++it) {
        int g = it * 256 + tid;
        if (g < 1100) {
            int z = g / 110, r = g - z * 110, y = r / 11, xx = r - y * 11;
            int gz = z0 + z, gy = y0 + y, gx = x0 + xx;
            bool inb = (unsigned)gz < 64u && (unsigned)gy < 64u && (unsigned)gx < 64u;
            uint4 a0 = ra[it], a1 = rb4[it];
            if (!inb) { a0 = make_uint4(0u, 0u, 0u, 0u); a1 = a0; }
            tile[g]        = a0;
            tile[1100 + g] = a1;
        }
    }
    __syncthreads();

    const int dy = tid & 1, dz = (tid >> 1) & 1;
    const int qx = (tid >> 2) & 3, Y = (tid >> 4) & 3, Z = (tid >> 6) & 3;
    const int cx0 = 2 * qx, cy = 2 * Y + dy, cz = 2 * Z + dz;

    float acc[2][4] = {{0.f, 0.f, 0.f, 0.f}, {0.f, 0.f, 0.f, 0.f}};

    #pragma unroll
    for (int kz = 0; kz < 3; ++kz)
    #pragma unroll
    for (int ky = 0; ky < 3; ++ky) {
        const int rb = (cz + kz) * 110 + (cy + ky) * 11 + cx0;
        h2_t hp[2][4][4];
        #pragma unroll
        for (int hh = 0; hh < 2; ++hh)
        #pragma unroll
        for (int xi = 0; xi < 4; ++xi) {
            U16 a; a.u = tile[hh * 1100 + rb + xi];
            #pragma unroll
            for (int p = 0; p < 4; ++p) hp[hh][xi][p] = a.h2[p];
        }
        const int t3 = (kz * 3 + ky) * 3;
        #pragma unroll
        for (int kx = 0; kx < 3; ++kx) {
            const h2_t* w = &w2L[(t3 + kx) * 32];   // uniform -> LDS broadcast
            #pragma unroll
            for (int j = 0; j < 2; ++j) {
                #pragma unroll
                for (int co = 0; co < 4; ++co) {
                    float a = acc[j][co];
                    #pragma unroll
                    for (int hh = 0; hh < 2; ++hh)
                    #pragma unroll
                    for (int p = 0; p < 4; ++p)
                        a = dot2f(hp[hh][kx + j][p], w[co * 8 + 4 * hh + p], a);
                    acc[j][co] = a;
                }
            }
        }
    }

    // ---- mask + relu + pool ----
    const int gcz = bz * 8 + cz, gcy = by * 8 + cy, gcx = bx * 8 + cx0;
    const float mv0 = m1[((b * 64 + gcz) * 64 + gcy) * 64 + gcx];
    const float mv1 = m1[((b * 64 + gcz) * 64 + gcy) * 64 + gcx + 1];
    float m = fmaxf(mv0, mv1);
    float r0 = fmaxf(fmaxf(acc[0][0], 0.f) * mv0, fmaxf(acc[1][0], 0.f) * mv1);
    float r1 = fmaxf(fmaxf(acc[0][1], 0.f) * mv0, fmaxf(acc[1][1], 0.f) * mv1);
    float r2 = fmaxf(fmaxf(acc[0][2], 0.f) * mv0, fmaxf(acc[1][2], 0.f) * mv1);
    float r3 = fmaxf(fmaxf(acc[0][3], 0.f) * mv0, fmaxf(acc[1][3], 0.f) * mv1);

    #pragma unroll
    for (int mask = 1; mask <= 2; mask <<= 1) {
        r0 = fmaxf(r0, __shfl_xor(r0, mask));
        r1 = fmaxf(r1, __shfl_xor(r1, mask));
        r2 = fmaxf(r2, __shfl_xor(r2, mask));
        r3 = fmaxf(r3, __shfl_xor(r3, mask));
        m  = fmaxf(m,  __shfl_xor(m,  mask));
    }
    if ((tid & 3) == 0) {
        int p = Z * 16 + Y * 4 + qx;
        sh_h[p] = make_float4(r0, r1, r2, r3);
        sh_m[p] = m;
    }
    __syncthreads();

    // ---- decoder phase: thread = (parent p, a, bb) ----
    {
        const int p  = tid >> 2;
        const int a  = (tid >> 1) & 1;
        const int bb = tid & 1;
        const int pZ = p >> 4, pY = (p >> 2) & 3, pq = p & 3;
        const int pz = bz * 4 + pZ, py = by * 4 + pY, pxq = bx * 4 + pq;

        const float mm = sh_m[p];
        const float4 hv = sh_h[p];

        const int b0q = ((((1 - a) * 2 + (1 - bb)) * 2) + 1) * 16;  // c=0 -> kc=1
        const int b1q = ((((1 - a) * 2 + (1 - bb)) * 2) + 0) * 16;  // c=1 -> kc=0
        float4 t0q[4], t1q[4];
        #pragma unroll
        for (int q = 0; q < 4; ++q) {
            float4 a0 = wt1[b0q + q],      a1 = wt1[b0q + 4 + q];
            float4 a2 = wt1[b0q + 8 + q],  a3 = wt1[b0q + 12 + q];
            float4 c0 = wt1[b1q + q],      c1 = wt1[b1q + 4 + q];
            float4 c2 = wt1[b1q + 8 + q],  c3 = wt1[b1q + 12 + q];
            float4 s0, s1;
            s0.x = hv.x * a0.x + hv.y * a1.x + hv.z * a2.x + hv.w * a3.x;
            s0.y = hv.x * a0.y + hv.y * a1.y + hv.z * a2.y + hv.w * a3.y;
            s0.z = hv.x * a0.z + hv.y * a1.z + hv.z * a2.z + hv.w * a3.z;
            s0.w = hv.x * a0.w + hv.y * a1.w + hv.z * a2.w + hv.w * a3.w;
            s1.x = hv.x * c0.x + hv.y * c1.x + hv.z * c2.x + hv.w * c3.x;
            s1.y = hv.x * c0.y + hv.y * c1.y + hv.z * c2.y + hv.w * c3.y;
            s1.z = hv.x * c0.z + hv.y * c1.z + hv.z * c2.z + hv.w * c3.z;
            s1.w = hv.x * c0.w + hv.y * c1.w + hv.z * c2.w + hv.w * c3.w;
            t0q[q] = make_float4(fmaxf(s0.x, 0.f), fmaxf(s0.y, 0.f),
                                 fmaxf(s0.z, 0.f), fmaxf(s0.w, 0.f));
            t1q[q] = make_float4(fmaxf(s1.x, 0.f), fmaxf(s1.y, 0.f),
                                 fmaxf(s1.z, 0.f), fmaxf(s1.w, 0.f));
        }

        #pragma unroll
        for (int e = 0; e < 2; ++e) {
            #pragma unroll
            for (int f = 0; f < 2; ++f) {
                const int d  = 4 * pz + 2 * a + e;
                const int hh = 4 * py + 2 * bb + f;
                const int be = ((1 - e) * 2 + (1 - f)) * 2;
                const float4* wg0 = &wt2[(be + 1) * 4];   // g=0 -> kg=1
                const float4* wg1 = &wt2[(be + 0) * 4];   // g=1 -> kg=0
                float s00 = dot4(t0q[0], wg0[0]) + dot4(t0q[1], wg0[1])
                          + dot4(t0q[2], wg0[2]) + dot4(t0q[3], wg0[3]);
                float s01 = dot4(t0q[0], wg1[0]) + dot4(t0q[1], wg1[1])
                          + dot4(t0q[2], wg1[2]) + dot4(t0q[3], wg1[3]);
                float s10 = dot4(t1q[0], wg0[0]) + dot4(t1q[1], wg0[1])
                          + dot4(t1q[2], wg0[2]) + dot4(t1q[3], wg0[3]);
                float s11 = dot4(t1q[0], wg1[0]) + dot4(t1q[1], wg1[1])
                          + dot4(t1q[2], wg1[2]) + dot4(t1q[3], wg1[3]);
                float4 o;
                o.x = mm / (1.f + __expf(-s00));
                o.y = mm / (1.f + __expf(-s01));
                o.z = mm / (1.f + __expf(-s10));
                o.w = mm / (1.f + __expf(-s11));
                *(float4*)&out[((b * G + d) * G + hh) * G + 4 * pxq] = o;
            }
        }
    }
}

extern "C" void kernel_launch(void* const* d_in, const int* in_sizes, int n_in,
                              void* d_out, int out_size, void* d_ws, size_t ws_size,
                              hipStream_t stream) {
    (void)in_sizes; (void)n_in; (void)out_size; (void)ws_size;
    const float* x   = (const float*)d_in[0];
    const float* W1  = (const float*)d_in[1];
    const float* W2  = (const float*)d_in[2];
    const float* Wt1 = (const float*)d_in[3];
    const float* Wt2 = (const float*)d_in[4];
    const int*   occ = (const int*)d_in[5];
    float* out = (float*)d_out;

    char* ws = (char*)d_ws;
    __half* h1p = (__half*)ws;                                  // 16 MB
    float*  m1  = (float*)(ws + 8388608ull * sizeof(__half));   // 2 MB

    k_conv1_pool<<<dim3(8, 8, 32), dim3(256), 0, stream>>>(x, occ, W1, h1p, m1);
    k_conv2_dec<<<dim3(8, 8, 16), dim3(256), 0, stream>>>(h1p, m1, W2, Wt1, Wt2, out);
}